// Round 9
// baseline (441.142 us; speedup 1.0000x reference)
//
#include <hip/hip_runtime.h>
#include <cstddef>

#define T_LEN 131072
#define CHUNK_T 128                 // timesteps owned by each scan block
#define NBLK (T_LEN / CHUNK_T)      // 1024 scan blocks
#define WARMUP 64                   // warmup steps; h converges from 0 (proven)
#define PTB 128                     // timesteps per prep block (4 waves x 32 t)

typedef float float4_t __attribute__((ext_vector_type(4)));

__device__ __forceinline__ float fast_sigmoid(float x) {
  float e = __builtin_amdgcn_exp2f(x * -1.44269504088896340736f);
  return __builtin_amdgcn_rcpf(1.0f + e);
}

__device__ __forceinline__ float fast_tanh(float x) {
  float e = __builtin_amdgcn_exp2f(x * 2.88539008177792681472f);
  return 1.0f - 2.0f * __builtin_amdgcn_rcpf(1.0f + e);
}

__device__ __forceinline__ float __rflf(float x) {
  return __builtin_bit_cast(float,
      __builtin_amdgcn_readfirstlane(__builtin_bit_cast(int, x)));
}

#define REP9(X) X(0) X(1) X(2) X(3) X(4) X(5) X(6) X(7) X(8)
#define REP64(X) \
  X(0) X(1) X(2) X(3) X(4) X(5) X(6) X(7) \
  X(8) X(9) X(10) X(11) X(12) X(13) X(14) X(15) \
  X(16) X(17) X(18) X(19) X(20) X(21) X(22) X(23) \
  X(24) X(25) X(26) X(27) X(28) X(29) X(30) X(31) \
  X(32) X(33) X(34) X(35) X(36) X(37) X(38) X(39) \
  X(40) X(41) X(42) X(43) X(44) X(45) X(46) X(47) \
  X(48) X(49) X(50) X(51) X(52) X(53) X(54) X(55) \
  X(56) X(57) X(58) X(59) X(60) X(61) X(62) X(63)
// (k, k&3) pairs for 4-subacc ILP
#define REP64P(X) \
  X(0,0) X(1,1) X(2,2) X(3,3) X(4,0) X(5,1) X(6,2) X(7,3) \
  X(8,0) X(9,1) X(10,2) X(11,3) X(12,0) X(13,1) X(14,2) X(15,3) \
  X(16,0) X(17,1) X(18,2) X(19,3) X(20,0) X(21,1) X(22,2) X(23,3) \
  X(24,0) X(25,1) X(26,2) X(27,3) X(28,0) X(29,1) X(30,2) X(31,3) \
  X(32,0) X(33,1) X(34,2) X(35,3) X(36,0) X(37,1) X(38,2) X(39,3) \
  X(40,0) X(41,1) X(42,2) X(43,3) X(44,0) X(45,1) X(46,2) X(47,3) \
  X(48,0) X(49,1) X(50,2) X(51,3) X(52,0) X(53,1) X(54,2) X(55,3) \
  X(56,0) X(57,1) X(58,2) X(59,3) X(60,0) X(61,1) X(62,2) X(63,3)

// ===========================================================================
// Kernel A (prep7): ZERO-DS gate precompute (scan1w structure, no recurrence).
// R15 diagnosis of prep6 (190us): its 22 shfl/shfl_xor per wave-t are
// ds_bpermute -> 16 waves/CU x 128t x 22 x ~6cyc ~ 110us of SERIAL per-CU
// DS-pipe time (SQ_LDS_BANK_CONFLICT 393K confirms). prep7: lane j holds
// FULL gate columns Wir/Wiz/Win[:,j] (192 VGPRs) + W1[:,j] (36) — legal at
// 1 wave/SIMD (<=512 VGPR budget, launch_bounds(256,1)). Each wave owns 32
// DISTINCT t (no redundancy): x lane-uniform loads + 36 readfirstlane
// (VALU), h1 = 36 FMA, broadcast via 64 v_readlane (VALU!), 192 FMA, 3
// coalesced stores. ~700cyc/wave-t, zero DS ops in the loop.
// ===========================================================================
#define DECLWI3(k) float wir##k, wiz##k, win##k;
#define INIWIR(k) wir##k = wstage[(k) * 64 + j];
#define INIWIZ(k) wiz##k = wstage[(k) * 64 + j];
#define INIWIN(k) win##k = wstage[(k) * 64 + j];
#define PINWI3(k) asm volatile("" : "+v"(wir##k), "+v"(wiz##k), "+v"(win##k));

#define DECLW1(c) float w1##c##0, w1##c##1, w1##c##2, w1##c##3;
#define INITW1(c) \
  w1##c##0 = wstage[((c)*4 + 0) * 64 + j]; \
  w1##c##1 = wstage[((c)*4 + 1) * 64 + j]; \
  w1##c##2 = wstage[((c)*4 + 2) * 64 + j]; \
  w1##c##3 = wstage[((c)*4 + 3) * 64 + j];
#define PINW1(c) asm volatile("" : "+v"(w1##c##0), "+v"(w1##c##1), \
                                   "+v"(w1##c##2), "+v"(w1##c##3));

#define DECLXV(c) float4_t xv##c;
#define LDXV(c) xv##c = xp[c];
#define CVT9(c) \
  const float xs##c##0 = __rflf(xv##c.x); \
  const float xs##c##1 = __rflf(xv##c.y); \
  const float xs##c##2 = __rflf(xv##c.z); \
  const float xs##c##3 = __rflf(xv##c.w);
#define H1C(c) \
  a0 = __builtin_fmaf(xs##c##0, w1##c##0, a0); \
  a1 = __builtin_fmaf(xs##c##1, w1##c##1, a1); \
  a2 = __builtin_fmaf(xs##c##2, w1##c##2, a2); \
  a3 = __builtin_fmaf(xs##c##3, w1##c##3, a3);

// one k of all three gates: readlane (VALU) + 3 FMA into chain a
#define GL(k, a) { \
  const float hg = __builtin_bit_cast(float, \
      __builtin_amdgcn_readlane(__builtin_bit_cast(int, h1), (k))); \
  r##a = __builtin_fmaf(wir##k, hg, r##a); \
  z##a = __builtin_fmaf(wiz##k, hg, z##a); \
  n##a = __builtin_fmaf(win##k, hg, n##a); }

__global__ __launch_bounds__(256, 1) void prep7_kernel(
    const float* __restrict__ obs, const float* __restrict__ W1,
    const float* __restrict__ b1,
    const float* __restrict__ Wir, const float* __restrict__ bir,
    const float* __restrict__ Wiz, const float* __restrict__ biz,
    const float* __restrict__ Win, const float* __restrict__ bin,
    float* __restrict__ gates)
{
  __shared__ float wstage[4096];        // 16 KB, init staging only

  const int tid = threadIdx.x;
  const int j = tid & 63;            // lane == gate column
  const int wid = tid >> 6;          // wave 0..3, owns 32 distinct t

  // ---- stage full gate columns into 192 VGPRs (3 rounds) -----------------
  REP64(DECLWI3)
  for (int i = tid; i < 4096; i += 256) wstage[i] = Wir[i];
  __syncthreads();
  REP64(INIWIR)
  __syncthreads();
  for (int i = tid; i < 4096; i += 256) wstage[i] = Wiz[i];
  __syncthreads();
  REP64(INIWIZ)
  __syncthreads();
  for (int i = tid; i < 4096; i += 256) wstage[i] = Win[i];
  __syncthreads();
  REP64(INIWIN)
  __syncthreads();
  // ---- W1 column j into 36 VGPRs -----------------------------------------
  REP9(DECLW1)
  for (int i = tid; i < 2304; i += 256) wstage[i] = W1[i];
  __syncthreads();
  REP9(INITW1)
  REP64(PINWI3)
  REP9(PINW1)

  float b1v = b1[j];
  float bR = bir[j], bZ = biz[j], bN = bin[j];
  asm volatile("" : "+v"(b1v), "+v"(bR), "+v"(bZ), "+v"(bN));

  const int t0 = blockIdx.x * PTB + wid * 32;

  // prefetch x(t0) (lane-uniform addresses -> one cache line per load)
  REP9(DECLXV)
  {
    const float4_t* xp = (const float4_t*)(obs + (size_t)t0 * 36);
    REP9(LDXV)
  }

  for (int tt = 0; tt < 32; ++tt) {
    // convert current x to SGPRs (vmcnt wait: loads are ~1 iteration old)
    REP9(CVT9)
    // issue next-t x loads (clamped in-range at the tail; value discarded)
    {
      const int tn = (tt < 31) ? tt + 1 : tt;
      const float4_t* xp = (const float4_t*)(obs + (size_t)(t0 + tn) * 36);
      REP9(LDXV)
    }
    // h1[j] = relu(b1 + x . W1[:,j])   (4 ILP chains)
    float a0 = b1v, a1 = 0.f, a2 = 0.f, a3 = 0.f;
    REP9(H1C)
    const float h1 = fmaxf((a0 + a1) + (a2 + a3), 0.0f);
    // full 64-k gate dots, h1 broadcast via readlane (4 ILP chains/gate)
    float r0 = bR, r1 = 0.f, r2 = 0.f, r3 = 0.f;
    float z0 = bZ, z1 = 0.f, z2 = 0.f, z3 = 0.f;
    float n0 = bN, n1 = 0.f, n2 = 0.f, n3 = 0.f;
    REP64P(GL)
    float* gp = gates + (size_t)(t0 + tt) * 192;
    gp[j]       = (r0 + r1) + (r2 + r3);
    gp[64 + j]  = (z0 + z1) + (z2 + z3);
    gp[128 + j] = (n0 + n1) + (n2 + n3);
  }
}

// ===========================================================================
// Kernel B (scan1w): SINGLE-WAVE chunk-parallel GRU scan, out-proj fused.
// (FROZEN from R8 — passed, absmax 0.0078125. After prep7 shrinks, this
// becomes the top dispatch and its counters become visible.)
// ===========================================================================
#define DECLWH(k) float whr##k, whz##k, whn##k;
#define INIWHR(k) whr##k = wstage[(k) * 64 + j];
#define INIWHZ(k) whz##k = wstage[(k) * 64 + j];
#define INIWHN(k) whn##k = wstage[(k) * 64 + j];
#define PINWH(k) asm volatile("" : "+v"(whr##k), "+v"(whz##k), "+v"(whn##k));

#define SRL(k, a) { \
  const float hh = __builtin_bit_cast(float, \
      __builtin_amdgcn_readlane(__builtin_bit_cast(int, h), (k))); \
  r##a = __builtin_fmaf(whr##k, hh, r##a); \
  z##a = __builtin_fmaf(whz##k, hh, z##a); \
  n##a = __builtin_fmaf(whn##k, hh, n##a); }

#define STEP1W(xr_, xz_, xn_) { \
  float r0=0.f,r1=0.f,r2=0.f,r3=0.f; \
  float z0=0.f,z1=0.f,z2=0.f,z3=0.f; \
  float n0=0.f,n1=0.f,n2=0.f,n3=0.f; \
  REP64P(SRL) \
  const float gr = fast_sigmoid((xr_) + ((r0 + r1) + (r2 + r3))); \
  const float gz = fast_sigmoid((xz_) + ((z0 + z1) + (z2 + z3))); \
  const float gn = fast_tanh((xn_) + gr * (((n0 + n1) + (n2 + n3)) + bh)); \
  h = gn + gz * (h - gn); }

__global__ __launch_bounds__(64, 1) void scan1w_kernel(
    const float* __restrict__ gates,
    const float* __restrict__ Whr, const float* __restrict__ Whz,
    const float* __restrict__ Whn, const float* __restrict__ bhn,
    const float* __restrict__ Wend, const float* __restrict__ bend,
    float* __restrict__ out)
{
  __shared__ __attribute__((aligned(16))) float wstage[4096];   // 16 KB init
  __shared__ __attribute__((aligned(16))) float hstage[16 * 68]; // padded ring
  __shared__ __attribute__((aligned(16))) float wendT[4 * 68];   // perm applied

  const int j = threadIdx.x;     // 0..63, lane == column

  // ---- stage Wh* into 192 VGPRs (3 rounds; single wave => no barriers,
  //      same-array aliasing pins ds_write/ds_read program order) ----------
  REP64(DECLWH)
  {
    const float4_t* s4 = (const float4_t*)Whr;
    float4_t* d4 = (float4_t*)wstage;
    for (int i = j; i < 1024; i += 64) d4[i] = s4[i];
  }
  REP64(INIWHR)
  {
    const float4_t* s4 = (const float4_t*)Whz;
    float4_t* d4 = (float4_t*)wstage;
    for (int i = j; i < 1024; i += 64) d4[i] = s4[i];
  }
  REP64(INIWHZ)
  {
    const float4_t* s4 = (const float4_t*)Whn;
    float4_t* d4 = (float4_t*)wstage;
    for (int i = j; i < 1024; i += 64) d4[i] = s4[i];
  }
  REP64(INIWHN)
  REP64(PINWH)

  // wendT[o][k] = Wend[k][o^1]  (perm = [1,0,3,2] = o^1), row stride 68
  for (int e = j; e < 256; e += 64) {
    const int o = e & 3, k = e >> 2;
    wendT[o * 68 + k] = Wend[k * 4 + (o ^ 1)];
  }
  const float bev = bend[(j & 3) ^ 1];
  float bh = bhn[j];
  asm volatile("" : "+v"(bh));

  // ---- slice geometry (unchanged) -----------------------------------------
  const int b = blockIdx.x;                  // 0..1023
  const int wu = (b == 0) ? 0 : WARMUP;
  const int nst = wu + CHUNK_T;              // 128 or 192 steps
  const float* gb = gates + (size_t)(b * CHUNK_T - wu) * 192;

  float h = 0.0f;

  // prefetch gate triples for s=0 and s=1
  float ra = gb[j],           za = gb[64 + j],       na = gb[128 + j];
  float rb = gb[192 + j],     zb = gb[256 + j],      nb = gb[320 + j];

  for (int s = 0; s < nst; s += 2) {
    {   // even step: consume (ra,za,na), prefetch s+2 (clamped in-range)
      const float xr = ra, xz = za, xn = na;
      const int sn = (s + 2 < nst) ? s + 2 : 0;     // tail: discard, in-range
      const float* gp = gb + (size_t)sn * 192;
      ra = gp[j]; za = gp[64 + j]; na = gp[128 + j];
      STEP1W(xr, xz, xn)
      hstage[(s & 15) * 68 + j] = h;
    }
    {   // odd step: consume (rb,zb,nb), prefetch s+3 (clamped in-range)
      const float xr = rb, xz = zb, xn = nb;
      const int sn = (s + 3 < nst) ? s + 3 : 0;
      const float* gp = gb + (size_t)sn * 192;
      rb = gp[j]; zb = gp[64 + j]; nb = gp[128 + j];
      STEP1W(xr, xz, xn)
      const int sp1 = s + 1;
      hstage[(sp1 & 15) * 68 + j] = h;
      if ((sp1 & 15) == 15 && sp1 >= wu) {
        // fused out-projection for the completed 16-step chunk
        const int tt = j >> 2, o = j & 3;
        const float4_t* hr = (const float4_t*)(hstage + tt * 68);
        const float4_t* wr = (const float4_t*)(wendT + o * 68);
        float acc = bev;
#pragma unroll
        for (int i = 0; i < 16; i++) {
          const float4_t hv = hr[i], wv = wr[i];
          acc += hv.x * wv.x + hv.y * wv.y + hv.z * wv.z + hv.w * wv.w;
        }
        const int t15 = b * CHUNK_T - wu + sp1 - 15;   // global t of row 0
        out[(size_t)t15 * 4 + j] = acc;   // tt*4+o == j: 256B coalesced
      }
    }
  }
}

// ---------------------------------------------------------------------------
extern "C" void kernel_launch(void* const* d_in, const int* in_sizes, int n_in,
                              void* d_out, int out_size, void* d_ws, size_t ws_size,
                              hipStream_t stream) {
  (void)in_sizes; (void)n_in; (void)out_size; (void)ws_size;
  const float* obs  = (const float*)d_in[0];
  const float* W1   = (const float*)d_in[1];
  const float* b1   = (const float*)d_in[2];
  const float* Wir  = (const float*)d_in[3];
  const float* bir  = (const float*)d_in[4];
  const float* Wiz  = (const float*)d_in[5];
  const float* biz  = (const float*)d_in[6];
  const float* Win  = (const float*)d_in[7];
  const float* bin  = (const float*)d_in[8];
  const float* Whr  = (const float*)d_in[9];
  const float* Whz  = (const float*)d_in[10];
  const float* Whn  = (const float*)d_in[11];
  const float* bhn  = (const float*)d_in[12];
  const float* Wend = (const float*)d_in[13];
  const float* bend = (const float*)d_in[14];
  float* out = (float*)d_out;

  float* gates = (float*)d_ws;                    // [T,3,64] fp32 = 100.7 MB

  prep7_kernel<<<T_LEN / PTB, 256, 0, stream>>>(obs, W1, b1, Wir, bir, Wiz, biz,
                                                Win, bin, gates);
  scan1w_kernel<<<NBLK, 64, 0, stream>>>(gates, Whr, Whz, Whn, bhn,
                                         Wend, bend, out);
}

// Round 10
// 403.852 us; speedup vs baseline: 1.0923x; 1.0923x over previous
//
#include <hip/hip_runtime.h>
#include <cstddef>

#define T_LEN 131072
#define CHUNK_T 64                  // timesteps owned by each scan block
#define NBLK (T_LEN / CHUNK_T)      // 2048 scan blocks -> 2 waves/SIMD
#define WARMUP 64                   // warmup steps; h converges from 0 (proven)
#define PTB 128                     // timesteps per prep block (4 waves x 32 t)

typedef float float4_t __attribute__((ext_vector_type(4)));
typedef float float2_t __attribute__((ext_vector_type(2)));

__device__ __forceinline__ float fast_sigmoid(float x) {
  float e = __builtin_amdgcn_exp2f(x * -1.44269504088896340736f);
  return __builtin_amdgcn_rcpf(1.0f + e);
}

__device__ __forceinline__ float fast_tanh(float x) {
  float e = __builtin_amdgcn_exp2f(x * 2.88539008177792681472f);
  return 1.0f - 2.0f * __builtin_amdgcn_rcpf(1.0f + e);
}

__device__ __forceinline__ float __rflf(float x) {
  return __builtin_bit_cast(float,
      __builtin_amdgcn_readfirstlane(__builtin_bit_cast(int, x)));
}

#define REP9(X) X(0) X(1) X(2) X(3) X(4) X(5) X(6) X(7) X(8)
#define REP64(X) \
  X(0) X(1) X(2) X(3) X(4) X(5) X(6) X(7) \
  X(8) X(9) X(10) X(11) X(12) X(13) X(14) X(15) \
  X(16) X(17) X(18) X(19) X(20) X(21) X(22) X(23) \
  X(24) X(25) X(26) X(27) X(28) X(29) X(30) X(31) \
  X(32) X(33) X(34) X(35) X(36) X(37) X(38) X(39) \
  X(40) X(41) X(42) X(43) X(44) X(45) X(46) X(47) \
  X(48) X(49) X(50) X(51) X(52) X(53) X(54) X(55) \
  X(56) X(57) X(58) X(59) X(60) X(61) X(62) X(63)
// (k, k&3) pairs for 4-subacc ILP
#define REP64P(X) \
  X(0,0) X(1,1) X(2,2) X(3,3) X(4,0) X(5,1) X(6,2) X(7,3) \
  X(8,0) X(9,1) X(10,2) X(11,3) X(12,0) X(13,1) X(14,2) X(15,3) \
  X(16,0) X(17,1) X(18,2) X(19,3) X(20,0) X(21,1) X(22,2) X(23,3) \
  X(24,0) X(25,1) X(26,2) X(27,3) X(28,0) X(29,1) X(30,2) X(31,3) \
  X(32,0) X(33,1) X(34,2) X(35,3) X(36,0) X(37,1) X(38,2) X(39,3) \
  X(40,0) X(41,1) X(42,2) X(43,3) X(44,0) X(45,1) X(46,2) X(47,3) \
  X(48,0) X(49,1) X(50,2) X(51,3) X(52,0) X(53,1) X(54,2) X(55,3) \
  X(56,0) X(57,1) X(58,2) X(59,3) X(60,0) X(61,1) X(62,2) X(63,3)

// ===========================================================================
// Kernel A (prep8): zero-DS-broadcast gate precompute, REGISTER-DIETED.
// R16 diagnosis: prep7/scan1w pinned >256 floats/wave -> compiler parked
// them in AGPRs (scan1w VGPR_Count=124 proves it) -> ~190 v_accvgpr_read
// per step (VALUBusy-derived 1000cyc/step = 2x estimate) + 1 wave/SIMD so
// nothing hides latency. prep8 diet: gate weights packed as 64x float2
// (wir,wiz) + 64x float (win) = 192 regs; W1 -> LDS (36 conflict-free
// ds_read_b32/t; DS pipe idle at this occupancy); x float4 depth-1
// prefetch (36 regs). ~250 regs => launch_bounds(256,2) => 2 waves/SIMD,
// arch-VGPR resident. (r,z) dots become v_pk_fma_f32 via <2 x float>
// mul+add (hipcc -ffp-contract=fast).
// ===========================================================================
#define DECLWIP(k) float2_t wirz##k; float winn##k;
#define INIWIR(k) wirz##k.x = wstage[(k) * 64 + j];
#define INIWIZ(k) wirz##k.y = wstage[(k) * 64 + j];
#define INIWIN(k) winn##k = wstage[(k) * 64 + j];
#define PINWIP(k) asm volatile("" : "+v"(wirz##k), "+v"(winn##k));

#define DECLXV(c) float4_t xv##c;
#define LDXV(c) xv##c = xp[c];
#define CVT9(c) \
  const float xs##c##0 = __rflf(xv##c.x); \
  const float xs##c##1 = __rflf(xv##c.y); \
  const float xs##c##2 = __rflf(xv##c.z); \
  const float xs##c##3 = __rflf(xv##c.w);
#define H1L(c) \
  a0 = __builtin_fmaf(xs##c##0, w1buf[((c)*4 + 0) * 64 + j], a0); \
  a1 = __builtin_fmaf(xs##c##1, w1buf[((c)*4 + 1) * 64 + j], a1); \
  a2 = __builtin_fmaf(xs##c##2, w1buf[((c)*4 + 2) * 64 + j], a2); \
  a3 = __builtin_fmaf(xs##c##3, w1buf[((c)*4 + 3) * 64 + j], a3);

#define GLP(k, a) { \
  const float hg = __builtin_bit_cast(float, \
      __builtin_amdgcn_readlane(__builtin_bit_cast(int, h1), (k))); \
  const float2_t h2 = {hg, hg}; \
  rz##a = wirz##k * h2 + rz##a; \
  n##a = __builtin_fmaf(winn##k, hg, n##a); }

__global__ __launch_bounds__(256, 2) void prep8_kernel(
    const float* __restrict__ obs, const float* __restrict__ W1,
    const float* __restrict__ b1,
    const float* __restrict__ Wir, const float* __restrict__ bir,
    const float* __restrict__ Wiz, const float* __restrict__ biz,
    const float* __restrict__ Win, const float* __restrict__ bin,
    float* __restrict__ gates)
{
  __shared__ float wstage[4096];        // 16 KB: gate-weight staging (init)
  __shared__ float w1buf[2304];         // 9.2 KB: W1, read 36x per t

  const int tid = threadIdx.x;
  const int j = tid & 63;            // lane == gate column
  const int wid = tid >> 6;          // wave 0..3, owns 32 distinct t

  REP64(DECLWIP)
  for (int i = tid; i < 4096; i += 256) wstage[i] = Wir[i];
  __syncthreads();
  REP64(INIWIR)
  __syncthreads();
  for (int i = tid; i < 4096; i += 256) wstage[i] = Wiz[i];
  __syncthreads();
  REP64(INIWIZ)
  __syncthreads();
  for (int i = tid; i < 4096; i += 256) wstage[i] = Win[i];
  __syncthreads();
  REP64(INIWIN)
  REP64(PINWIP)
  for (int i = tid; i < 2304; i += 256) w1buf[i] = W1[i];
  __syncthreads();

  float b1v = b1[j];
  float2_t brz = {bir[j], biz[j]};
  float bN = bin[j];
  asm volatile("" : "+v"(b1v), "+v"(brz), "+v"(bN));

  const int t0 = blockIdx.x * PTB + wid * 32;

  // prefetch x(t0) (lane-uniform addresses -> one cache line per load)
  REP9(DECLXV)
  {
    const float4_t* xp = (const float4_t*)(obs + (size_t)t0 * 36);
    REP9(LDXV)
  }

  for (int tt = 0; tt < 32; ++tt) {
    // convert current x to SGPRs (vmcnt wait: loads are ~1 iteration old)
    REP9(CVT9)
    // issue next-t x loads (clamped in-range at the tail; value discarded)
    {
      const int tn = (tt < 31) ? tt + 1 : tt;
      const float4_t* xp = (const float4_t*)(obs + (size_t)(t0 + tn) * 36);
      REP9(LDXV)
    }
    // h1[j] = relu(b1 + x . W1[:,j])   (W1 from LDS, 4 ILP chains)
    float a0 = b1v, a1 = 0.f, a2 = 0.f, a3 = 0.f;
    REP9(H1L)
    const float h1 = fmaxf((a0 + a1) + (a2 + a3), 0.0f);
    // full 64-k gate dots: (r,z) packed pk_fma, n scalar; readlane bcast
    float2_t rz0 = brz, rz1 = {0.f, 0.f}, rz2 = {0.f, 0.f}, rz3 = {0.f, 0.f};
    float n0 = bN, n1 = 0.f, n2 = 0.f, n3 = 0.f;
    REP64P(GLP)
    const float2_t rzs = (rz0 + rz1) + (rz2 + rz3);
    float* gp = gates + (size_t)(t0 + tt) * 192;
    gp[j]       = rzs.x;
    gp[64 + j]  = rzs.y;
    gp[128 + j] = (n0 + n1) + (n2 + n3);
  }
}

// ===========================================================================
// Kernel B (scan1w): single-wave chunk-parallel GRU scan, reg-dieted.
// R16: CHUNK_T 128->64 => 2048 blocks = 2 waves/SIMD (co-resident wave
// hides latency); launch_bounds(64,2) => 256-reg budget so the 192 weights
// live in ARCH VGPRs (no accvgpr moves — R9's VGPR_Count=124 exposed them);
// (whr,whz) packed as float2 -> v_pk_fma_f32 halves the r/z issue. LDS cut
// to one 16KB buffer (hstage/wendT overlaid after weight staging) so 8
// blocks/CU fit. Step machinery otherwise identical to the proven R8 scan.
// ===========================================================================
#define DECLWH(k) float2_t wrz##k; float whn##k;
#define INIWHR(k) wrz##k.x = smem[(k) * 64 + j];
#define INIWHZ(k) wrz##k.y = smem[(k) * 64 + j];
#define INIWHN(k) whn##k = smem[(k) * 64 + j];
#define PINWH(k) asm volatile("" : "+v"(wrz##k), "+v"(whn##k));

#define SRL(k, a) { \
  const float hh = __builtin_bit_cast(float, \
      __builtin_amdgcn_readlane(__builtin_bit_cast(int, h), (k))); \
  const float2_t h2 = {hh, hh}; \
  rz##a = wrz##k * h2 + rz##a; \
  n##a = __builtin_fmaf(whn##k, hh, n##a); }

#define STEP1W(xr_, xz_, xn_) { \
  float2_t rz0 = {0.f,0.f}, rz1 = {0.f,0.f}, rz2 = {0.f,0.f}, rz3 = {0.f,0.f}; \
  float n0=0.f,n1=0.f,n2=0.f,n3=0.f; \
  REP64P(SRL) \
  const float2_t rzs = (rz0 + rz1) + (rz2 + rz3); \
  const float gr = fast_sigmoid((xr_) + rzs.x); \
  const float gz = fast_sigmoid((xz_) + rzs.y); \
  const float gn = fast_tanh((xn_) + gr * (((n0 + n1) + (n2 + n3)) + bh)); \
  h = gn + gz * (h - gn); }

__global__ __launch_bounds__(64, 2) void scan1w_kernel(
    const float* __restrict__ gates,
    const float* __restrict__ Whr, const float* __restrict__ Whz,
    const float* __restrict__ Whn, const float* __restrict__ bhn,
    const float* __restrict__ Wend, const float* __restrict__ bend,
    float* __restrict__ out)
{
  // one 16KB buffer: weight staging at init; afterwards hstage (0..1087)
  // and wendT (1088..1359) overlay it. Single wave => program order.
  __shared__ __attribute__((aligned(16))) float smem[4096];
  float* const hstage = smem;            // 16 rows x 68 (padded)
  float* const wendT  = smem + 1088;     // 4 rows x 68

  const int j = threadIdx.x;     // 0..63, lane == column

  REP64(DECLWH)
  {
    const float4_t* s4 = (const float4_t*)Whr;
    float4_t* d4 = (float4_t*)smem;
    for (int i = j; i < 1024; i += 64) d4[i] = s4[i];
  }
  REP64(INIWHR)
  {
    const float4_t* s4 = (const float4_t*)Whz;
    float4_t* d4 = (float4_t*)smem;
    for (int i = j; i < 1024; i += 64) d4[i] = s4[i];
  }
  REP64(INIWHZ)
  {
    const float4_t* s4 = (const float4_t*)Whn;
    float4_t* d4 = (float4_t*)smem;
    for (int i = j; i < 1024; i += 64) d4[i] = s4[i];
  }
  REP64(INIWHN)
  REP64(PINWH)

  // wendT[o][k] = Wend[k][o^1]  (perm = [1,0,3,2] = o^1), row stride 68
  for (int e = j; e < 256; e += 64) {
    const int o = e & 3, k = e >> 2;
    wendT[o * 68 + k] = Wend[k * 4 + (o ^ 1)];
  }
  const float bev = bend[(j & 3) ^ 1];
  float bh = bhn[j];
  asm volatile("" : "+v"(bh));

  // ---- slice geometry -----------------------------------------------------
  const int b = blockIdx.x;                  // 0..2047
  const int wu = (b == 0) ? 0 : WARMUP;
  const int nst = wu + CHUNK_T;              // 64 or 128 steps
  const float* gb = gates + (size_t)(b * CHUNK_T - wu) * 192;

  float h = 0.0f;

  // prefetch gate triples for s=0 and s=1
  float ra = gb[j],           za = gb[64 + j],       na = gb[128 + j];
  float rb = gb[192 + j],     zb = gb[256 + j],      nb = gb[320 + j];

  for (int s = 0; s < nst; s += 2) {
    {   // even step: consume (ra,za,na), prefetch s+2 (clamped in-range)
      const float xr = ra, xz = za, xn = na;
      const int sn = (s + 2 < nst) ? s + 2 : 0;     // tail: discard, in-range
      const float* gp = gb + (size_t)sn * 192;
      ra = gp[j]; za = gp[64 + j]; na = gp[128 + j];
      STEP1W(xr, xz, xn)
      hstage[(s & 15) * 68 + j] = h;
    }
    {   // odd step: consume (rb,zb,nb), prefetch s+3 (clamped in-range)
      const float xr = rb, xz = zb, xn = nb;
      const int sn = (s + 3 < nst) ? s + 3 : 0;
      const float* gp = gb + (size_t)sn * 192;
      rb = gp[j]; zb = gp[64 + j]; nb = gp[128 + j];
      STEP1W(xr, xz, xn)
      const int sp1 = s + 1;
      hstage[(sp1 & 15) * 68 + j] = h;
      if ((sp1 & 15) == 15 && sp1 >= wu) {
        // fused out-projection for the completed 16-step chunk
        const int tt = j >> 2, o = j & 3;
        const float4_t* hr = (const float4_t*)(hstage + tt * 68);
        const float4_t* wr = (const float4_t*)(wendT + o * 68);
        float acc = bev;
#pragma unroll
        for (int i = 0; i < 16; i++) {
          const float4_t hv = hr[i], wv = wr[i];
          acc += hv.x * wv.x + hv.y * wv.y + hv.z * wv.z + hv.w * wv.w;
        }
        const int t15 = b * CHUNK_T - wu + sp1 - 15;   // global t of row 0
        out[(size_t)t15 * 4 + j] = acc;   // tt*4+o == j: 256B coalesced
      }
    }
  }
}

// ---------------------------------------------------------------------------
extern "C" void kernel_launch(void* const* d_in, const int* in_sizes, int n_in,
                              void* d_out, int out_size, void* d_ws, size_t ws_size,
                              hipStream_t stream) {
  (void)in_sizes; (void)n_in; (void)out_size; (void)ws_size;
  const float* obs  = (const float*)d_in[0];
  const float* W1   = (const float*)d_in[1];
  const float* b1   = (const float*)d_in[2];
  const float* Wir  = (const float*)d_in[3];
  const float* bir  = (const float*)d_in[4];
  const float* Wiz  = (const float*)d_in[5];
  const float* biz  = (const float*)d_in[6];
  const float* Win  = (const float*)d_in[7];
  const float* bin  = (const float*)d_in[8];
  const float* Whr  = (const float*)d_in[9];
  const float* Whz  = (const float*)d_in[10];
  const float* Whn  = (const float*)d_in[11];
  const float* bhn  = (const float*)d_in[12];
  const float* Wend = (const float*)d_in[13];
  const float* bend = (const float*)d_in[14];
  float* out = (float*)d_out;

  float* gates = (float*)d_ws;                    // [T,3,64] fp32 = 100.7 MB

  prep8_kernel<<<T_LEN / PTB, 256, 0, stream>>>(obs, W1, b1, Wir, bir, Wiz, biz,
                                                Win, bin, gates);
  scan1w_kernel<<<NBLK, 64, 0, stream>>>(gates, Whr, Whz, Whn, bhn,
                                         Wend, bend, out);
}

// Round 11
// 356.546 us; speedup vs baseline: 1.2373x; 1.1327x over previous
//
#include <hip/hip_runtime.h>
#include <cstddef>

#define T_LEN 131072
#define CHUNK_T 128                 // timesteps owned by each scan block
#define NBLK (T_LEN / CHUNK_T)      // 1024 scan blocks = 1 wave/SIMD
#define WARMUP 64                   // warmup steps; h converges from 0 (proven)

typedef float float4_t __attribute__((ext_vector_type(4)));
typedef float float2_t __attribute__((ext_vector_type(2)));

__device__ __forceinline__ float fast_sigmoid(float x) {
  float e = __builtin_amdgcn_exp2f(x * -1.44269504088896340736f);
  return __builtin_amdgcn_rcpf(1.0f + e);
}

__device__ __forceinline__ float fast_tanh(float x) {
  float e = __builtin_amdgcn_exp2f(x * 2.88539008177792681472f);
  return 1.0f - 2.0f * __builtin_amdgcn_rcpf(1.0f + e);
}

#define REP64(X) \
  X(0) X(1) X(2) X(3) X(4) X(5) X(6) X(7) \
  X(8) X(9) X(10) X(11) X(12) X(13) X(14) X(15) \
  X(16) X(17) X(18) X(19) X(20) X(21) X(22) X(23) \
  X(24) X(25) X(26) X(27) X(28) X(29) X(30) X(31) \
  X(32) X(33) X(34) X(35) X(36) X(37) X(38) X(39) \
  X(40) X(41) X(42) X(43) X(44) X(45) X(46) X(47) \
  X(48) X(49) X(50) X(51) X(52) X(53) X(54) X(55) \
  X(56) X(57) X(58) X(59) X(60) X(61) X(62) X(63)
// (k, k&3) pairs for 4-subacc ILP
#define REP64P(X) \
  X(0,0) X(1,1) X(2,2) X(3,3) X(4,0) X(5,1) X(6,2) X(7,3) \
  X(8,0) X(9,1) X(10,2) X(11,3) X(12,0) X(13,1) X(14,2) X(15,3) \
  X(16,0) X(17,1) X(18,2) X(19,3) X(20,0) X(21,1) X(22,2) X(23,3) \
  X(24,0) X(25,1) X(26,2) X(27,3) X(28,0) X(29,1) X(30,2) X(31,3) \
  X(32,0) X(33,1) X(34,2) X(35,3) X(36,0) X(37,1) X(38,2) X(39,3) \
  X(40,0) X(41,1) X(42,2) X(43,3) X(44,0) X(45,1) X(46,2) X(47,3) \
  X(48,0) X(49,1) X(50,2) X(51,3) X(52,0) X(53,1) X(54,2) X(55,3) \
  X(56,0) X(57,1) X(58,2) X(59,3) X(60,0) X(61,1) X(62,2) X(63,3)

// ===========================================================================
// Kernel A (prep9): prep2 (R3, proven ~145us) + hbuf BANK-CONFLICT FIX.
// R17 post-mortem: every "weights-in-VGPR" prep since R5 was secretly
// spill-resident (prep8: VGPR=128, +51MB scratch WRITE_SIZE proves the
// "+v" pin doesn't keep values live). Reverting to the proven DS-broadcast
// prep2 and fixing its one diagnosed flaw: hrow reads at stride 256B were
// a 16-way bank conflict (~5.7x on 48 of ~240 DS insts/wave-t). hbuf rows
// padded 64->68 floats => bank index 4*tt mod 32 => 2-way (free, m136).
// LDS 34.4KB => 4 blocks/CU, bounds(256,4).
// ===========================================================================
__global__ __launch_bounds__(256, 4) void prep9_kernel(
    const float* __restrict__ obs, const float* __restrict__ W1,
    const float* __restrict__ b1,
    const float* __restrict__ Wir, const float* __restrict__ bir,
    const float* __restrict__ Wiz, const float* __restrict__ biz,
    const float* __restrict__ Win, const float* __restrict__ bin,
    float* __restrict__ gates)
{
  __shared__ float wbuf[4096];      // 16KB: W1 (2304 used), then Wir/Wiz/Win
  __shared__ float hbuf[64 * 68];   // 17KB: hs_in rows, PADDED to 68 floats
  __shared__ float sb1[64];
  __shared__ float sbg[192];        // bir | biz | bin

  const int tid = threadIdx.x;
  const int tt  = tid >> 2;         // local timestep 0..63
  const int q   = tid & 3;          // output quarter (16 cols)
  const int t   = blockIdx.x * 64 + tt;

  // stage W1 + all biases
  for (int i = tid; i < 2304; i += 256) wbuf[i] = W1[i];
  if (tid < 64) {
    sb1[tid] = b1[tid];
    sbg[tid] = bir[tid];
    sbg[64 + tid] = biz[tid];
    sbg[128 + tid] = bin[tid];
  }
  __syncthreads();

  // ---- phase 1: h[tt][q*16 .. q*16+15] = relu(x @ W1 + b1) ---------------
  {
    float4_t x4[9];
    const float4_t* op = (const float4_t*)(obs + (size_t)t * 36);
#pragma unroll
    for (int c = 0; c < 9; c++) x4[c] = op[c];

    float4_t h4[4];
    {
      const float4_t* bv = (const float4_t*)(sb1 + q * 16);
#pragma unroll
      for (int k = 0; k < 4; k++) h4[k] = bv[k];
    }
#pragma unroll
    for (int c = 0; c < 9; c++) {
#pragma unroll
      for (int e = 0; e < 4; e++) {
        const float xv = x4[c][e];
        const float4_t* wrow = (const float4_t*)(wbuf + (c * 4 + e) * 64 + q * 16);
#pragma unroll
        for (int k = 0; k < 4; k++) h4[k] += xv * wrow[k];
      }
    }
    float4_t* hdst = (float4_t*)(hbuf + tt * 68 + q * 16);
#pragma unroll
    for (int k = 0; k < 4; k++) {
      float4_t v = h4[k];
      v.x = fmaxf(v.x, 0.0f); v.y = fmaxf(v.y, 0.0f);
      v.z = fmaxf(v.z, 0.0f); v.w = fmaxf(v.w, 0.0f);
      hdst[k] = v;
    }
  }
  __syncthreads();   // hbuf complete; W1 reads of wbuf drained

  // ---- phase 2: gates, g-outer, weight matrix staged per gate ------------
  for (int g = 0; g < 3; g++) {
    const float* wsrc = (g == 0) ? Wir : (g == 1) ? Wiz : Win;
    for (int i = tid; i < 4096; i += 256) wbuf[i] = wsrc[i];
    __syncthreads();

    float4_t acc[4];
    {
      const float4_t* bv = (const float4_t*)(sbg + g * 64 + q * 16);
#pragma unroll
      for (int k = 0; k < 4; k++) acc[k] = bv[k];
    }
    const float4_t* hrow = (const float4_t*)(hbuf + tt * 68);
    for (int kk = 0; kk < 16; kk++) {       // rolled: keeps regs low
      const float4_t hv = hrow[kk];
#pragma unroll
      for (int e = 0; e < 4; e++) {
        const float h = hv[e];
        const float4_t* wrow = (const float4_t*)(wbuf + (kk * 4 + e) * 64 + q * 16);
#pragma unroll
        for (int k = 0; k < 4; k++) acc[k] += h * wrow[k];
      }
    }
    float4_t* gout = (float4_t*)(gates + (size_t)t * 192 + g * 64 + q * 16);
#pragma unroll
    for (int k = 0; k < 4; k++) gout[k] = acc[k];
    __syncthreads();   // wbuf reads drained before restage
  }
}

// ===========================================================================
// Kernel B (scan1w v3): single-wave chunk-parallel GRU scan, R8 config
// (CHUNK 128, 1024 blocks, bounds(64,1)) + ONE isolated change vs R8:
// (whr,whz) packed as float2 -> v_pk_fma_f32, halving r/z FMA issue
// (192 -> 128 VALU ops/step). If scan is issue-bound (R9: 39% VALUBusy at
// 1 wave/SIMD => ~1000 issue-cyc/step) this is a direct cut; if unchanged,
// the scan is stall-bound and the counters now visible will say which.
// ===========================================================================
#define DECLWH(k) float2_t wrz##k; float whn##k;
#define INIWHR(k) wrz##k.x = smem[(k) * 64 + j];
#define INIWHZ(k) wrz##k.y = smem[(k) * 64 + j];
#define INIWHN(k) whn##k = smem[(k) * 64 + j];
#define PINWH(k) asm volatile("" : "+v"(wrz##k), "+v"(whn##k));

#define SRL(k, a) { \
  const float hh = __builtin_bit_cast(float, \
      __builtin_amdgcn_readlane(__builtin_bit_cast(int, h), (k))); \
  const float2_t h2 = {hh, hh}; \
  rz##a = wrz##k * h2 + rz##a; \
  n##a = __builtin_fmaf(whn##k, hh, n##a); }

#define STEP1W(xr_, xz_, xn_) { \
  float2_t rz0 = {0.f,0.f}, rz1 = {0.f,0.f}, rz2 = {0.f,0.f}, rz3 = {0.f,0.f}; \
  float n0=0.f,n1=0.f,n2=0.f,n3=0.f; \
  REP64P(SRL) \
  const float2_t rzs = (rz0 + rz1) + (rz2 + rz3); \
  const float gr = fast_sigmoid((xr_) + rzs.x); \
  const float gz = fast_sigmoid((xz_) + rzs.y); \
  const float gn = fast_tanh((xn_) + gr * (((n0 + n1) + (n2 + n3)) + bh)); \
  h = gn + gz * (h - gn); }

__global__ __launch_bounds__(64, 1) void scan1w_kernel(
    const float* __restrict__ gates,
    const float* __restrict__ Whr, const float* __restrict__ Whz,
    const float* __restrict__ Whn, const float* __restrict__ bhn,
    const float* __restrict__ Wend, const float* __restrict__ bend,
    float* __restrict__ out)
{
  // one 16KB buffer: weight staging at init; afterwards hstage (0..1087)
  // and wendT (1088..1359) overlay it. Single wave => program order.
  __shared__ __attribute__((aligned(16))) float smem[4096];
  float* const hstage = smem;            // 16 rows x 68 (padded)
  float* const wendT  = smem + 1088;     // 4 rows x 68

  const int j = threadIdx.x;     // 0..63, lane == column

  REP64(DECLWH)
  {
    const float4_t* s4 = (const float4_t*)Whr;
    float4_t* d4 = (float4_t*)smem;
    for (int i = j; i < 1024; i += 64) d4[i] = s4[i];
  }
  REP64(INIWHR)
  {
    const float4_t* s4 = (const float4_t*)Whz;
    float4_t* d4 = (float4_t*)smem;
    for (int i = j; i < 1024; i += 64) d4[i] = s4[i];
  }
  REP64(INIWHZ)
  {
    const float4_t* s4 = (const float4_t*)Whn;
    float4_t* d4 = (float4_t*)smem;
    for (int i = j; i < 1024; i += 64) d4[i] = s4[i];
  }
  REP64(INIWHN)
  REP64(PINWH)

  // wendT[o][k] = Wend[k][o^1]  (perm = [1,0,3,2] = o^1), row stride 68
  for (int e = j; e < 256; e += 64) {
    const int o = e & 3, k = e >> 2;
    wendT[o * 68 + k] = Wend[k * 4 + (o ^ 1)];
  }
  const float bev = bend[(j & 3) ^ 1];
  float bh = bhn[j];
  asm volatile("" : "+v"(bh));

  // ---- slice geometry (R8-proven) -----------------------------------------
  const int b = blockIdx.x;                  // 0..1023
  const int wu = (b == 0) ? 0 : WARMUP;
  const int nst = wu + CHUNK_T;              // 128 or 192 steps
  const float* gb = gates + (size_t)(b * CHUNK_T - wu) * 192;

  float h = 0.0f;

  // prefetch gate triples for s=0 and s=1
  float ra = gb[j],           za = gb[64 + j],       na = gb[128 + j];
  float rb = gb[192 + j],     zb = gb[256 + j],      nb = gb[320 + j];

  for (int s = 0; s < nst; s += 2) {
    {   // even step: consume (ra,za,na), prefetch s+2 (clamped in-range)
      const float xr = ra, xz = za, xn = na;
      const int sn = (s + 2 < nst) ? s + 2 : 0;     // tail: discard, in-range
      const float* gp = gb + (size_t)sn * 192;
      ra = gp[j]; za = gp[64 + j]; na = gp[128 + j];
      STEP1W(xr, xz, xn)
      hstage[(s & 15) * 68 + j] = h;
    }
    {   // odd step: consume (rb,zb,nb), prefetch s+3 (clamped in-range)
      const float xr = rb, xz = zb, xn = nb;
      const int sn = (s + 3 < nst) ? s + 3 : 0;
      const float* gp = gb + (size_t)sn * 192;
      rb = gp[j]; zb = gp[64 + j]; nb = gp[128 + j];
      STEP1W(xr, xz, xn)
      const int sp1 = s + 1;
      hstage[(sp1 & 15) * 68 + j] = h;
      if ((sp1 & 15) == 15 && sp1 >= wu) {
        // fused out-projection for the completed 16-step chunk
        const int tt = j >> 2, o = j & 3;
        const float4_t* hr = (const float4_t*)(hstage + tt * 68);
        const float4_t* wr = (const float4_t*)(wendT + o * 68);
        float acc = bev;
#pragma unroll
        for (int i = 0; i < 16; i++) {
          const float4_t hv = hr[i], wv = wr[i];
          acc += hv.x * wv.x + hv.y * wv.y + hv.z * wv.z + hv.w * wv.w;
        }
        const int t15 = b * CHUNK_T - wu + sp1 - 15;   // global t of row 0
        out[(size_t)t15 * 4 + j] = acc;   // tt*4+o == j: 256B coalesced
      }
    }
  }
}

// ---------------------------------------------------------------------------
extern "C" void kernel_launch(void* const* d_in, const int* in_sizes, int n_in,
                              void* d_out, int out_size, void* d_ws, size_t ws_size,
                              hipStream_t stream) {
  (void)in_sizes; (void)n_in; (void)out_size; (void)ws_size;
  const float* obs  = (const float*)d_in[0];
  const float* W1   = (const float*)d_in[1];
  const float* b1   = (const float*)d_in[2];
  const float* Wir  = (const float*)d_in[3];
  const float* bir  = (const float*)d_in[4];
  const float* Wiz  = (const float*)d_in[5];
  const float* biz  = (const float*)d_in[6];
  const float* Win  = (const float*)d_in[7];
  const float* bin  = (const float*)d_in[8];
  const float* Whr  = (const float*)d_in[9];
  const float* Whz  = (const float*)d_in[10];
  const float* Whn  = (const float*)d_in[11];
  const float* bhn  = (const float*)d_in[12];
  const float* Wend = (const float*)d_in[13];
  const float* bend = (const float*)d_in[14];
  float* out = (float*)d_out;

  float* gates = (float*)d_ws;                    // [T,3,64] fp32 = 100.7 MB

  prep9_kernel<<<T_LEN / 64, 256, 0, stream>>>(obs, W1, b1, Wir, bir, Wiz, biz,
                                               Win, bin, gates);
  scan1w_kernel<<<NBLK, 64, 0, stream>>>(gates, Whr, Whz, Whn, bhn,
                                         Wend, bend, out);
}